// Round 3
// baseline (215.957 us; speedup 1.0000x reference)
//
#include <hip/hip_runtime.h>

// g(act) lookup: TN uniform nodes over act=[0,1], table[i] = g(i/(TN-1)).
// Table has TN+1 entries so the hot loop's tab[i+1] read is valid at i=TN-1
// (act==1.0 -> frac==0, the extra entry's value is never weighted in).
#define TN 4096
#define TABN (TN + 1)
#define BLOCK 512                 // 8 waves/block; 4 blocks/CU = 32 waves/CU (cap)
#define ITERS 16                  // patches per thread in main kernel
#define PER_BLOCK (BLOCK * ITERS) // 8192 patches per block -> 1024 blocks, all resident
#define TBLOCK 256                // block size for table-fill / tail kernels

typedef float f4 __attribute__((ext_vector_type(4)));

// exp-based tanh: no libm branches, v_exp_f32 path.
__device__ inline float fast_tanh(float x) {
    x = fminf(fmaxf(x, -10.f), 10.f);
    float e = __expf(2.f * x);
    return (e - 1.f) / (e + 1.f);
}

// Full reference math for one scalar activation value (runs only TABN times).
__device__ float eval_g(float act,
                        const float* __restrict__ basis,
                        const float* __restrict__ w1,
                        const float* __restrict__ b1,
                        const float* __restrict__ w2,
                        const float* __restrict__ b2) {
    float feats[8];
#pragma unroll
    for (int b = 0; b < 8; ++b) {
        float s = 0.f;
#pragma unroll
        for (int k = 0; k < 4; ++k) {
            float d = act - basis[b * 4 + k];
            s = fmaf(d, d, s);
        }
        feats[b] = __expf(-s);   // GAMMA = 1
    }
    float out = b2[0];
#pragma unroll
    for (int j = 0; j < 16; ++j) {
        float u = b1[j];
#pragma unroll
        for (int b = 0; b < 8; ++b) u = fmaf(feats[b], w1[b * 16 + j], u);
        out = fmaf(fast_tanh(u), w2[j], out);
    }
    return out;
}

__global__ __launch_bounds__(TBLOCK)
void fill_table_kernel(const float* __restrict__ basis,
                       const float* __restrict__ w1,
                       const float* __restrict__ b1,
                       const float* __restrict__ w2,
                       const float* __restrict__ b2,
                       float* __restrict__ table) {
    int i = blockIdx.x * TBLOCK + threadIdx.x;
    if (i >= TABN) return;
    const float inv = 1.0f / (float)(TN - 1);
    int node = (i < TN) ? i : (TN - 1);     // entry TN repeats the last node
    float a = (float)node * inv;
    table[i] = eval_g(a, basis, w1, b1, w2, b2);
}

// One patch: conv -> sigmoid -> table-lerp -> nt store.
__device__ inline void proc_one(f4 d, float cw0, float cw1, float cw2, float cw3,
                                float cb, const float* __restrict__ tab,
                                float* __restrict__ op, int off) {
    float logit = fmaf(d.x, cw0, fmaf(d.y, cw1, fmaf(d.z, cw2, fmaf(d.w, cw3, cb))));
    float e = __expf(-logit);                    // v_exp path
    float act = __builtin_amdgcn_rcpf(1.0f + e); // sigmoid
    float t = act * (float)(TN - 1);             // t in [0, 4095]
    unsigned int i = (unsigned int)t;            // act>=0; i<=4095
    float frac = t - (float)i;
    float y0 = tab[i];                           // ds_read2_b32 pair
    float y1 = tab[i + 1];
    float r = fmaf(frac, y1 - y0, y0);
    __builtin_nontemporal_store(r, &op[off]);    // out is never re-read
}

// Hot kernel: grid covers exactly gridDim.x*PER_BLOCK patches (no bounds
// check). Remainder handled by hybridconv_tail (not taken at N=8.4M).
// 1024 blocks -> 4 blocks/CU, entire grid resident in one round.
// Data loads are PLAIN cached loads this round (R3 A/B: nt-read removal).
__global__ __launch_bounds__(BLOCK, 8)
void hybridconv_main(const f4* __restrict__ data,
                     const float* __restrict__ conv_w,
                     const float* __restrict__ conv_b,
                     const float* __restrict__ gtable,
                     float* __restrict__ out) {
    __shared__ __align__(16) float tab[TABN];

    const f4* __restrict__ dp = data + (size_t)blockIdx.x * PER_BLOCK + threadIdx.x;
    float* __restrict__ op = out + (size_t)blockIdx.x * PER_BLOCK + threadIdx.x;

    // Prefetch the first 4 data iterations BEFORE the table copy: their HBM
    // latency hides under the chip-wide table-copy burst at kernel start.
    f4 p0 = dp[0 * BLOCK];
    f4 p1 = dp[1 * BLOCK];
    f4 p2 = dp[2 * BLOCK];
    f4 p3 = dp[3 * BLOCK];

    // cooperative table copy, float4-wide: 1024 float4 / 512 threads = 2 each
    {
        const f4* __restrict__ g4 = (const f4*)gtable;
        f4* t4 = (f4*)tab;
#pragma unroll
        for (int i = 0; i < (TN / 4) / BLOCK; ++i)
            t4[threadIdx.x + i * BLOCK] = g4[threadIdx.x + i * BLOCK];
        if (threadIdx.x == 0) tab[TN] = gtable[TN];
    }
    __syncthreads();

    const float cw0 = conv_w[0], cw1 = conv_w[1], cw2 = conv_w[2], cw3 = conv_w[3];
    const float cb = conv_b[0];

    proc_one(p0, cw0, cw1, cw2, cw3, cb, tab, op, 0 * BLOCK);
    proc_one(p1, cw0, cw1, cw2, cw3, cb, tab, op, 1 * BLOCK);
    proc_one(p2, cw0, cw1, cw2, cw3, cb, tab, op, 2 * BLOCK);
    proc_one(p3, cw0, cw1, cw2, cw3, cb, tab, op, 3 * BLOCK);

#pragma unroll 4
    for (int k = 4; k < ITERS; ++k) {
        f4 d = dp[k * BLOCK];
        proc_one(d, cw0, cw1, cw2, cw3, cb, tab, op, k * BLOCK);
    }
}

// Bounds-checked scalar tail (never launches when n % PER_BLOCK == 0).
__global__ __launch_bounds__(TBLOCK)
void hybridconv_tail(const f4* __restrict__ data,
                     const float* __restrict__ conv_w,
                     const float* __restrict__ conv_b,
                     const float* __restrict__ gtable,
                     float* __restrict__ out, int start, int n) {
    int idx = start + blockIdx.x * TBLOCK + threadIdx.x;
    if (idx >= n) return;
    f4 d = data[idx];
    float logit = fmaf(d.x, conv_w[0], fmaf(d.y, conv_w[1],
                  fmaf(d.z, conv_w[2], fmaf(d.w, conv_w[3], conv_b[0]))));
    float e = __expf(-logit);
    float act = __builtin_amdgcn_rcpf(1.0f + e);
    float t = act * (float)(TN - 1);
    unsigned int i = (unsigned int)t;
    i = min(i, (unsigned int)(TN - 1));
    float frac = t - (float)i;
    float y0 = gtable[i];
    float y1 = gtable[i + 1];
    out[idx] = fmaf(frac, y1 - y0, y0);
}

extern "C" void kernel_launch(void* const* d_in, const int* in_sizes, int n_in,
                              void* d_out, int out_size, void* d_ws, size_t ws_size,
                              hipStream_t stream) {
    const f4* data      = (const f4*)d_in[0];
    const float* conv_w = (const float*)d_in[1];
    const float* conv_b = (const float*)d_in[2];
    const float* basis  = (const float*)d_in[3];
    const float* w1     = (const float*)d_in[4];
    const float* b1     = (const float*)d_in[5];
    const float* w2     = (const float*)d_in[6];
    const float* b2     = (const float*)d_in[7];
    float* out = (float*)d_out;
    float* table = (float*)d_ws;   // 16.4 KB scratch

    int n = out_size;  // N patches, one output each

    fill_table_kernel<<<dim3((TABN + TBLOCK - 1) / TBLOCK), dim3(TBLOCK), 0, stream>>>(
        basis, w1, b1, w2, b2, table);

    int full_blocks = n / PER_BLOCK;               // 1024 for N=8388608
    if (full_blocks > 0) {
        hybridconv_main<<<dim3(full_blocks), dim3(BLOCK), 0, stream>>>(
            data, conv_w, conv_b, table, out);
    }
    int start = full_blocks * PER_BLOCK;
    if (start < n) {                               // never taken for N=8388608
        int rem = n - start;
        hybridconv_tail<<<dim3((rem + TBLOCK - 1) / TBLOCK), dim3(TBLOCK), 0, stream>>>(
            data, conv_w, conv_b, table, out, start, n);
    }
}

// Round 4
// 203.329 us; speedup vs baseline: 1.0621x; 1.0621x over previous
//
#include <hip/hip_runtime.h>

// g(act) lookup: TN uniform nodes over act=[0,1], table[i] = g(i/(TN-1)).
// Table has TN+1 entries so the hot loop's tab[i+1] read is valid at i=TN-1
// (act==1.0 -> frac==0, the extra entry's value is never weighted in).
#define TN 4096
#define TABN (TN + 1)
#define BLOCK 512                 // 8 waves/block; 4 blocks/CU = 32 waves/CU (cap)
#define ITERS 16                  // patches per thread in main kernel
#define PER_BLOCK (BLOCK * ITERS) // 8192 patches per block -> 1024 blocks, all resident
#define TBLOCK 256                // block size for table-fill / tail kernels

typedef float f4 __attribute__((ext_vector_type(4)));

// exp-based tanh: no libm branches, v_exp_f32 path.
__device__ inline float fast_tanh(float x) {
    x = fminf(fmaxf(x, -10.f), 10.f);
    float e = __expf(2.f * x);
    return (e - 1.f) / (e + 1.f);
}

// Full reference math for one scalar activation value (runs only TABN times).
__device__ float eval_g(float act,
                        const float* __restrict__ basis,
                        const float* __restrict__ w1,
                        const float* __restrict__ b1,
                        const float* __restrict__ w2,
                        const float* __restrict__ b2) {
    float feats[8];
#pragma unroll
    for (int b = 0; b < 8; ++b) {
        float s = 0.f;
#pragma unroll
        for (int k = 0; k < 4; ++k) {
            float d = act - basis[b * 4 + k];
            s = fmaf(d, d, s);
        }
        feats[b] = __expf(-s);   // GAMMA = 1
    }
    float out = b2[0];
#pragma unroll
    for (int j = 0; j < 16; ++j) {
        float u = b1[j];
#pragma unroll
        for (int b = 0; b < 8; ++b) u = fmaf(feats[b], w1[b * 16 + j], u);
        out = fmaf(fast_tanh(u), w2[j], out);
    }
    return out;
}

__global__ __launch_bounds__(TBLOCK)
void fill_table_kernel(const float* __restrict__ basis,
                       const float* __restrict__ w1,
                       const float* __restrict__ b1,
                       const float* __restrict__ w2,
                       const float* __restrict__ b2,
                       float* __restrict__ table) {
    int i = blockIdx.x * TBLOCK + threadIdx.x;
    if (i >= TABN) return;
    const float inv = 1.0f / (float)(TN - 1);
    int node = (i < TN) ? i : (TN - 1);     // entry TN repeats the last node
    float a = (float)node * inv;
    table[i] = eval_g(a, basis, w1, b1, w2, b2);
}

// One patch: conv -> sigmoid -> table-lerp -> nt store.
__device__ inline void proc_one(f4 d, float cw0, float cw1, float cw2, float cw3,
                                float cb, const float* __restrict__ tab,
                                float* __restrict__ op, int off) {
    float logit = fmaf(d.x, cw0, fmaf(d.y, cw1, fmaf(d.z, cw2, fmaf(d.w, cw3, cb))));
    float e = __expf(-logit);                    // v_exp path
    float act = __builtin_amdgcn_rcpf(1.0f + e); // sigmoid
    float t = act * (float)(TN - 1);             // t in [0, 4095]
    unsigned int i = (unsigned int)t;            // act>=0; i<=4095
    float frac = t - (float)i;
    float y0 = tab[i];                           // ds_read2_b32 pair
    float y1 = tab[i + 1];
    float r = fmaf(frac, y1 - y0, y0);
    __builtin_nontemporal_store(r, &op[off]);    // out is never re-read
}

// Hot kernel: grid covers exactly gridDim.x*PER_BLOCK patches (no bounds
// check). Remainder handled by hybridconv_tail (not taken at N=8.4M).
// 1024 blocks -> 4 blocks/CU, entire grid resident in one round.
// NT loads are REQUIRED here (R3 A/B: removing them cost +11 us — streaming
// reads must bypass L2 so they don't thrash the out-stream/table lines).
// 2-stage ping-pong pipeline: group g+1's 4 nt-loads issue before group g is
// processed, keeping 8x16B/thread in flight past LDS/store backpressure.
__global__ __launch_bounds__(BLOCK, 8)
void hybridconv_main(const f4* __restrict__ data,
                     const float* __restrict__ conv_w,
                     const float* __restrict__ conv_b,
                     const float* __restrict__ gtable,
                     float* __restrict__ out) {
    __shared__ __align__(16) float tab[TABN];

    const f4* __restrict__ dp = data + (size_t)blockIdx.x * PER_BLOCK + threadIdx.x;
    float* __restrict__ op = out + (size_t)blockIdx.x * PER_BLOCK + threadIdx.x;

    // Prefetch group 0 BEFORE the table copy: HBM latency hides under the
    // chip-wide table-copy burst at kernel start.
    f4 a0 = __builtin_nontemporal_load(&dp[0 * BLOCK]);
    f4 a1 = __builtin_nontemporal_load(&dp[1 * BLOCK]);
    f4 a2 = __builtin_nontemporal_load(&dp[2 * BLOCK]);
    f4 a3 = __builtin_nontemporal_load(&dp[3 * BLOCK]);

    // cooperative table copy, float4-wide: 1024 float4 / 512 threads = 2 each
    {
        const f4* __restrict__ g4 = (const f4*)gtable;
        f4* t4 = (f4*)tab;
#pragma unroll
        for (int i = 0; i < (TN / 4) / BLOCK; ++i)
            t4[threadIdx.x + i * BLOCK] = g4[threadIdx.x + i * BLOCK];
        if (threadIdx.x == 0) tab[TN] = gtable[TN];
    }
    __syncthreads();

    const float cw0 = conv_w[0], cw1 = conv_w[1], cw2 = conv_w[2], cw3 = conv_w[3];
    const float cb = conv_b[0];

    // g=0: issue group1, process group0
    f4 b0 = __builtin_nontemporal_load(&dp[4 * BLOCK]);
    f4 b1v = __builtin_nontemporal_load(&dp[5 * BLOCK]);
    f4 b2v = __builtin_nontemporal_load(&dp[6 * BLOCK]);
    f4 b3 = __builtin_nontemporal_load(&dp[7 * BLOCK]);
    proc_one(a0, cw0, cw1, cw2, cw3, cb, tab, op, 0 * BLOCK);
    proc_one(a1, cw0, cw1, cw2, cw3, cb, tab, op, 1 * BLOCK);
    proc_one(a2, cw0, cw1, cw2, cw3, cb, tab, op, 2 * BLOCK);
    proc_one(a3, cw0, cw1, cw2, cw3, cb, tab, op, 3 * BLOCK);

    // g=1: issue group2, process group1
    a0 = __builtin_nontemporal_load(&dp[8 * BLOCK]);
    a1 = __builtin_nontemporal_load(&dp[9 * BLOCK]);
    a2 = __builtin_nontemporal_load(&dp[10 * BLOCK]);
    a3 = __builtin_nontemporal_load(&dp[11 * BLOCK]);
    proc_one(b0,  cw0, cw1, cw2, cw3, cb, tab, op, 4 * BLOCK);
    proc_one(b1v, cw0, cw1, cw2, cw3, cb, tab, op, 5 * BLOCK);
    proc_one(b2v, cw0, cw1, cw2, cw3, cb, tab, op, 6 * BLOCK);
    proc_one(b3,  cw0, cw1, cw2, cw3, cb, tab, op, 7 * BLOCK);

    // g=2: issue group3, process group2
    b0  = __builtin_nontemporal_load(&dp[12 * BLOCK]);
    b1v = __builtin_nontemporal_load(&dp[13 * BLOCK]);
    b2v = __builtin_nontemporal_load(&dp[14 * BLOCK]);
    b3  = __builtin_nontemporal_load(&dp[15 * BLOCK]);
    proc_one(a0, cw0, cw1, cw2, cw3, cb, tab, op, 8 * BLOCK);
    proc_one(a1, cw0, cw1, cw2, cw3, cb, tab, op, 9 * BLOCK);
    proc_one(a2, cw0, cw1, cw2, cw3, cb, tab, op, 10 * BLOCK);
    proc_one(a3, cw0, cw1, cw2, cw3, cb, tab, op, 11 * BLOCK);

    // g=3: process group3 (nothing left to issue)
    proc_one(b0,  cw0, cw1, cw2, cw3, cb, tab, op, 12 * BLOCK);
    proc_one(b1v, cw0, cw1, cw2, cw3, cb, tab, op, 13 * BLOCK);
    proc_one(b2v, cw0, cw1, cw2, cw3, cb, tab, op, 14 * BLOCK);
    proc_one(b3,  cw0, cw1, cw2, cw3, cb, tab, op, 15 * BLOCK);
}

// Bounds-checked scalar tail (never launches when n % PER_BLOCK == 0).
__global__ __launch_bounds__(TBLOCK)
void hybridconv_tail(const f4* __restrict__ data,
                     const float* __restrict__ conv_w,
                     const float* __restrict__ conv_b,
                     const float* __restrict__ gtable,
                     float* __restrict__ out, int start, int n) {
    int idx = start + blockIdx.x * TBLOCK + threadIdx.x;
    if (idx >= n) return;
    f4 d = data[idx];
    float logit = fmaf(d.x, conv_w[0], fmaf(d.y, conv_w[1],
                  fmaf(d.z, conv_w[2], fmaf(d.w, conv_w[3], conv_b[0]))));
    float e = __expf(-logit);
    float act = __builtin_amdgcn_rcpf(1.0f + e);
    float t = act * (float)(TN - 1);
    unsigned int i = (unsigned int)t;
    i = min(i, (unsigned int)(TN - 1));
    float frac = t - (float)i;
    float y0 = gtable[i];
    float y1 = gtable[i + 1];
    out[idx] = fmaf(frac, y1 - y0, y0);
}

extern "C" void kernel_launch(void* const* d_in, const int* in_sizes, int n_in,
                              void* d_out, int out_size, void* d_ws, size_t ws_size,
                              hipStream_t stream) {
    const f4* data      = (const f4*)d_in[0];
    const float* conv_w = (const float*)d_in[1];
    const float* conv_b = (const float*)d_in[2];
    const float* basis  = (const float*)d_in[3];
    const float* w1     = (const float*)d_in[4];
    const float* b1     = (const float*)d_in[5];
    const float* w2     = (const float*)d_in[6];
    const float* b2     = (const float*)d_in[7];
    float* out = (float*)d_out;
    float* table = (float*)d_ws;   // 16.4 KB scratch

    int n = out_size;  // N patches, one output each

    fill_table_kernel<<<dim3((TABN + TBLOCK - 1) / TBLOCK), dim3(TBLOCK), 0, stream>>>(
        basis, w1, b1, w2, b2, table);

    int full_blocks = n / PER_BLOCK;               // 1024 for N=8388608
    if (full_blocks > 0) {
        hybridconv_main<<<dim3(full_blocks), dim3(BLOCK), 0, stream>>>(
            data, conv_w, conv_b, table, out);
    }
    int start = full_blocks * PER_BLOCK;
    if (start < n) {                               // never taken for N=8388608
        int rem = n - start;
        hybridconv_tail<<<dim3((rem + TBLOCK - 1) / TBLOCK), dim3(TBLOCK), 0, stream>>>(
            data, conv_w, conv_b, table, out, start, n);
    }
}